// Round 1
// baseline (449.443 us; speedup 1.0000x reference)
//
#include <hip/hip_runtime.h>
#include <hip/hip_bf16.h>

// ScaledDotProductAttention: B=4 H=16 S=2048 D=64, fp32 in/out, key mask [B,1,1,S].
// Flash-attention forward, bf16 MFMA (16x16x32), fp32 softmax/accum.
// Layouts (m89-verified): A: row=l&15, k=(l>>4)*8+e ; B: col=l&15, k=(l>>4)*8+e ;
// C/D: col=l&15, row=(l>>4)*4+reg.

#define S_LEN 2048
#define D_DIM 64
#define KVB   64
#define QB    128   // q rows per block (4 waves x 32)
#define LDK   72    // padded LDS leading dim (bf16 elems)

typedef float  f32x4 __attribute__((ext_vector_type(4)));
typedef __bf16 bf8   __attribute__((ext_vector_type(8)));
typedef __bf16 bf4   __attribute__((ext_vector_type(4)));

__global__ void sdpa_kernel(const float* __restrict__ q, const float* __restrict__ k,
                            const float* __restrict__ v, const int* __restrict__ mask,
                            float* __restrict__ out) {
    const int bh   = blockIdx.x;          // 0..63 (b*H+h)
    const int qt   = blockIdx.y;          // 0..15
    const int b    = bh >> 4;             // H=16
    const int tid  = threadIdx.x;
    const int wave = tid >> 6;
    const int lane = tid & 63;
    const int lhi  = lane >> 4;           // 0..3
    const int llo  = lane & 15;           // 0..15

    __shared__ __bf16 Kl[64 * LDK];        // K tile, row-major [key][d]
    __shared__ __bf16 Vl[64 * LDK];        // V tile, TRANSPOSED [d][key]
    __shared__ __bf16 Pl[4][32 * LDK];     // per-wave P tile [qrow][key]

    const size_t base = (size_t)bh * S_LEN * D_DIM;

    // ---- Q fragments, scale 1/8 folded in (exact power-of-2) ----
    bf8 qf[2][2];
    const int qrow_base = qt * QB + wave * 32;
    #pragma unroll
    for (int m = 0; m < 2; ++m) {
        const float* qp = q + base + (size_t)(qrow_base + m * 16 + llo) * D_DIM;
        #pragma unroll
        for (int kk = 0; kk < 2; ++kk) {
            int d0 = kk * 32 + lhi * 8;
            float4 a  = *(const float4*)(qp + d0);
            float4 b4 = *(const float4*)(qp + d0 + 4);
            bf8 f;
            f[0] = (__bf16)(a.x  * 0.125f); f[1] = (__bf16)(a.y  * 0.125f);
            f[2] = (__bf16)(a.z  * 0.125f); f[3] = (__bf16)(a.w  * 0.125f);
            f[4] = (__bf16)(b4.x * 0.125f); f[5] = (__bf16)(b4.y * 0.125f);
            f[6] = (__bf16)(b4.z * 0.125f); f[7] = (__bf16)(b4.w * 0.125f);
            qf[m][kk] = f;
        }
    }

    f32x4 acc[2][4];
    #pragma unroll
    for (int m = 0; m < 2; ++m)
        #pragma unroll
        for (int n = 0; n < 4; ++n)
            acc[m][n] = (f32x4)(0.0f);

    float mrow[2][4], lrow[2][4];
    #pragma unroll
    for (int m = 0; m < 2; ++m)
        #pragma unroll
        for (int e = 0; e < 4; ++e) { mrow[m][e] = -INFINITY; lrow[m][e] = 0.0f; }

    for (int kv0 = 0; kv0 < S_LEN; kv0 += KVB) {
        __syncthreads();   // prior iteration's LDS reads done before restage

        // ---- stage K tile: row-major [key][d], coalesced float4 loads ----
        {
            int colg = (tid & 15) * 4;     // d
            int row0 = tid >> 4;           // 0..15
            #pragma unroll
            for (int p = 0; p < 4; ++p) {
                int row = row0 + p * 16;   // key
                float4 x = *(const float4*)(k + base + (size_t)(kv0 + row) * D_DIM + colg);
                bf4 s;
                s[0] = (__bf16)x.x; s[1] = (__bf16)x.y; s[2] = (__bf16)x.z; s[3] = (__bf16)x.w;
                *(bf4*)(&Kl[row * LDK + colg]) = s;
            }
        }
        // ---- stage V tile transposed: Vl[d][key]; d-major global reads stay coalesced ----
        {
            int d  = tid & 63;
            int kg = (tid >> 6) * 16;
            __bf16 tmp[16];
            #pragma unroll
            for (int j = 0; j < 16; ++j)
                tmp[j] = (__bf16)v[base + (size_t)(kv0 + kg + j) * D_DIM + d];
            *(bf8*)(&Vl[d * LDK + kg])     = *(bf8*)(&tmp[0]);
            *(bf8*)(&Vl[d * LDK + kg + 8]) = *(bf8*)(&tmp[8]);
        }
        __syncthreads();

        // ---- QK^T: P[32][64] per wave ----
        f32x4 p[2][4];
        #pragma unroll
        for (int m = 0; m < 2; ++m)
            #pragma unroll
            for (int n = 0; n < 4; ++n)
                p[m][n] = (f32x4)(0.0f);

        #pragma unroll
        for (int kk = 0; kk < 2; ++kk) {
            #pragma unroll
            for (int n = 0; n < 4; ++n) {
                bf8 kb = *(const bf8*)(&Kl[(n * 16 + llo) * LDK + kk * 32 + lhi * 8]);
                #pragma unroll
                for (int m = 0; m < 2; ++m)
                    p[m][n] = __builtin_amdgcn_mfma_f32_16x16x32_bf16(qf[m][kk], kb, p[m][n], 0, 0, 0);
            }
        }

        // ---- mask (key-broadcast): score = mask ? s : -1e9 ----
        #pragma unroll
        for (int n = 0; n < 4; ++n) {
            int mk = mask[b * S_LEN + kv0 + n * 16 + llo];
            if (mk == 0) {
                #pragma unroll
                for (int m = 0; m < 2; ++m)
                    #pragma unroll
                    for (int e = 0; e < 4; ++e)
                        p[m][n][e] = -1e9f;
            }
        }

        // ---- online softmax (rows spread over 16-lane groups; wave-parallel) ----
        #pragma unroll
        for (int m = 0; m < 2; ++m) {
            #pragma unroll
            for (int e = 0; e < 4; ++e) {
                float mx = fmaxf(fmaxf(p[m][0][e], p[m][1][e]), fmaxf(p[m][2][e], p[m][3][e]));
                mx = fmaxf(mx, __shfl_xor(mx, 1));
                mx = fmaxf(mx, __shfl_xor(mx, 2));
                mx = fmaxf(mx, __shfl_xor(mx, 4));
                mx = fmaxf(mx, __shfl_xor(mx, 8));
                float mn = fmaxf(mrow[m][e], mx);
                float sc = __expf(mrow[m][e] - mn);
                mrow[m][e] = mn;
                float rs = 0.0f;
                #pragma unroll
                for (int n = 0; n < 4; ++n) {
                    float pe = __expf(p[m][n][e] - mn);
                    p[m][n][e] = pe;
                    rs += pe;
                }
                rs += __shfl_xor(rs, 1);
                rs += __shfl_xor(rs, 2);
                rs += __shfl_xor(rs, 4);
                rs += __shfl_xor(rs, 8);
                lrow[m][e] = lrow[m][e] * sc + rs;
                #pragma unroll
                for (int n = 0; n < 4; ++n)
                    acc[m][n][e] *= sc;
            }
        }

        // ---- P -> LDS (bf16) to re-layout C-frag -> A-frag ----
        __bf16* pw = &Pl[wave][0];
        #pragma unroll
        for (int m = 0; m < 2; ++m)
            #pragma unroll
            for (int n = 0; n < 4; ++n)
                #pragma unroll
                for (int e = 0; e < 4; ++e)
                    pw[(m * 16 + lhi * 4 + e) * LDK + n * 16 + llo] = (__bf16)p[m][n][e];

        // ---- PV: O += P[32x64] * V[64x64] (compiler inserts lgkmcnt for own-wave RAW) ----
        #pragma unroll
        for (int kk = 0; kk < 2; ++kk) {
            bf8 pa[2];
            #pragma unroll
            for (int m = 0; m < 2; ++m)
                pa[m] = *(const bf8*)(&pw[(m * 16 + llo) * LDK + kk * 32 + lhi * 8]);
            #pragma unroll
            for (int n = 0; n < 4; ++n) {
                bf8 vb = *(const bf8*)(&Vl[(n * 16 + llo) * LDK + kk * 32 + lhi * 8]);
                #pragma unroll
                for (int m = 0; m < 2; ++m)
                    acc[m][n] = __builtin_amdgcn_mfma_f32_16x16x32_bf16(pa[m], vb, acc[m][n], 0, 0, 0);
            }
        }
    }

    // ---- epilogue: O = acc / l ----
    #pragma unroll
    for (int m = 0; m < 2; ++m) {
        #pragma unroll
        for (int e = 0; e < 4; ++e) {
            float inv = 1.0f / lrow[m][e];
            int row = qrow_base + m * 16 + lhi * 4 + e;
            float* op = out + base + (size_t)row * D_DIM;
            #pragma unroll
            for (int n = 0; n < 4; ++n)
                op[n * 16 + llo] = acc[m][n][e] * inv;
        }
    }
}

extern "C" void kernel_launch(void* const* d_in, const int* in_sizes, int n_in,
                              void* d_out, int out_size, void* d_ws, size_t ws_size,
                              hipStream_t stream) {
    (void)in_sizes; (void)n_in; (void)d_ws; (void)ws_size; (void)out_size;
    const float* q    = (const float*)d_in[0];
    const float* k    = (const float*)d_in[1];
    const float* v    = (const float*)d_in[2];
    const int*   mask = (const int*)d_in[3];
    // d_in[4] = dropout scalar, identity in eval reference.
    float* out = (float*)d_out;

    dim3 grid(64, 16);   // x = b*H+h, y = q-tile
    dim3 block(256);     // 4 waves x 32 q-rows
    sdpa_kernel<<<grid, block, 0, stream>>>(q, k, v, mask, out);
}

// Round 3
// 262.569 us; speedup vs baseline: 1.7117x; 1.7117x over previous
//
#include <hip/hip_runtime.h>
#include <hip/hip_bf16.h>

// SDPA B=4 H=16 S=2048 D=64 fp32 I/O, key mask [B,1,1,S].
// Swapped-operand flash attention (m214 structure), 32x32x16 bf16 MFMA.
// QK^T swapped: S^T = mfma(A=K, B=Q)  -> C col = q = lane&31, row = key = (r&3)+8*(r>>2)+4*hi
// PV  swapped: O^T = mfma(A=V^T, B=P) -> C col = q = lane&31, row = d
// => softmax stats (m,l) are lane-local scalars; P stays in registers
//    (bf16-pack + shfl_xor(32) + select rebuilds the B-fragment).

#define S_LEN 2048
#define D_DIM 64
#define KVB   64
#define QB    128   // q rows per block (4 waves x 32)
#define LDK   72    // padded LDS leading dim (bf16 elems)

typedef float  f32x16 __attribute__((ext_vector_type(16)));
typedef __bf16 bf8    __attribute__((ext_vector_type(8)));
typedef __bf16 bf4    __attribute__((ext_vector_type(4)));
typedef __bf16 bf2    __attribute__((ext_vector_type(2)));
typedef unsigned int u32x4 __attribute__((ext_vector_type(4)));

__global__ __launch_bounds__(256, 3)   // VGPR cap ~168: no spill risk at ~130 live, 12 waves/CU
void sdpa_kernel(const float* __restrict__ q, const float* __restrict__ k,
                 const float* __restrict__ v, const int* __restrict__ mask,
                 float* __restrict__ out) {
    const int bh   = blockIdx.x;          // b*H + h
    const int qt   = blockIdx.y;          // q tile
    const int b    = bh >> 4;             // H = 16
    const int tid  = threadIdx.x;
    const int wave = tid >> 6;
    const int lane = tid & 63;
    const int l31  = lane & 31;
    const int hi   = lane >> 5;           // 0/1: which half-wave

    __shared__ __bf16 Kl[64 * LDK];       // K tile row-major [key][d]
    __shared__ __bf16 Vt[64 * LDK];       // V tile transposed [d][key]

    const size_t base = (size_t)bh * (S_LEN * D_DIM);

    // ---- Q fragment (B-operand): Q[q = qrow][d = ds*16 + hi*8 + e], scale 1/8 folded ----
    const int qrow = qt * QB + wave * 32 + l31;
    bf8 qf[4];
    {
        const float* qp = q + base + (size_t)qrow * D_DIM;
        #pragma unroll
        for (int ds = 0; ds < 4; ++ds) {
            float4 a = *(const float4*)(qp + ds * 16 + hi * 8);
            float4 c = *(const float4*)(qp + ds * 16 + hi * 8 + 4);
            bf8 f;
            f[0] = (__bf16)(a.x * 0.125f); f[1] = (__bf16)(a.y * 0.125f);
            f[2] = (__bf16)(a.z * 0.125f); f[3] = (__bf16)(a.w * 0.125f);
            f[4] = (__bf16)(c.x * 0.125f); f[5] = (__bf16)(c.y * 0.125f);
            f[6] = (__bf16)(c.z * 0.125f); f[7] = (__bf16)(c.w * 0.125f);
            qf[ds] = f;
        }
    }

    f32x16 acc0 = (f32x16)0.0f;   // O^T, d 0..31
    f32x16 acc1 = (f32x16)0.0f;   // O^T, d 32..63
    float mrun = -INFINITY, lrun = 0.0f;

    for (int kv0 = 0; kv0 < S_LEN; kv0 += KVB) {
        __syncthreads();
        // ---- stage K [64 keys][64 d] ----
        {
            int colg = (tid & 15) * 4;
            int row0 = tid >> 4;
            #pragma unroll
            for (int pp = 0; pp < 4; ++pp) {
                int row = row0 + pp * 16;
                float4 x = *(const float4*)(k + base + (size_t)(kv0 + row) * D_DIM + colg);
                bf4 s;
                s[0] = (__bf16)x.x; s[1] = (__bf16)x.y; s[2] = (__bf16)x.z; s[3] = (__bf16)x.w;
                *(bf4*)(&Kl[row * LDK + colg]) = s;
            }
        }
        // ---- stage V^T [64 d][64 keys] (d-major global reads coalesced per j) ----
        {
            int d  = tid & 63;
            int kg = (tid >> 6) * 16;
            __bf16 tmp[16];
            #pragma unroll
            for (int j = 0; j < 16; ++j)
                tmp[j] = (__bf16)v[base + (size_t)(kv0 + kg + j) * D_DIM + d];
            *(bf8*)(&Vt[d * LDK + kg])     = *(bf8*)(&tmp[0]);
            *(bf8*)(&Vt[d * LDK + kg + 8]) = *(bf8*)(&tmp[8]);
        }
        __syncthreads();

        // ---- key mask bitmap for this 64-key tile (bit j = key kv0+j) ----
        unsigned long long bm = __ballot(mask[b * S_LEN + kv0 + lane] != 0);

        // ---- QK^T swapped: p0 = S^T keys 0..31, p1 = keys 32..63 ----
        f32x16 p0 = (f32x16)0.0f, p1 = (f32x16)0.0f;
        #pragma unroll
        for (int ds = 0; ds < 4; ++ds) {
            bf8 k0 = *(const bf8*)(&Kl[l31 * LDK        + ds * 16 + hi * 8]);
            bf8 k1 = *(const bf8*)(&Kl[(32 + l31) * LDK + ds * 16 + hi * 8]);
            p0 = __builtin_amdgcn_mfma_f32_32x32x16_bf16(k0, qf[ds], p0, 0, 0, 0);
            p1 = __builtin_amdgcn_mfma_f32_32x32x16_bf16(k1, qf[ds], p1, 0, 0, 0);
        }

        if (bm != ~0ull) {   // wave-uniform skip for the all-ones mask
            #pragma unroll
            for (int r = 0; r < 16; ++r) {
                int kr = (r & 3) + 8 * (r >> 2) + 4 * hi;
                if (!((bm >> kr) & 1))        p0[r] = -1e9f;
                if (!((bm >> (32 + kr)) & 1)) p1[r] = -1e9f;
            }
        }

        // ---- online softmax: lane + partner(lane^32) together hold all 64 keys of row q ----
        float mx = -INFINITY;
        #pragma unroll
        for (int r = 0; r < 16; ++r) mx = fmaxf(mx, fmaxf(p0[r], p1[r]));
        mx = fmaxf(mx, __shfl_xor(mx, 32));
        float mnew = fmaxf(mrun, mx);
        float sc = __expf(mrun - mnew);
        mrun = mnew;
        lrun *= sc;
        #pragma unroll
        for (int r = 0; r < 16; ++r) { acc0[r] *= sc; acc1[r] *= sc; }

        float rs = 0.0f;
        // ---- per 32-key block: exp, bf16-pack, half-wave exchange, PV ----
        auto do_kb = [&](f32x16& p, int kbbase) {
            #pragma unroll
            for (int r = 0; r < 16; ++r) { p[r] = __expf(p[r] - mnew); rs += p[r]; }
            // pack key pairs: lo holds keys {0-3,8-11,16-19,24-27}, hi holds +4.
            // wds[j] = bf16 pair of the lane's (2j,2j+1)-th held keys.
            unsigned wds[8], xw[8];
            #pragma unroll
            for (int j = 0; j < 8; ++j) {
                bf2 t; t[0] = (__bf16)p[2 * j]; t[1] = (__bf16)p[2 * j + 1];
                wds[j] = __builtin_bit_cast(unsigned, t);
            }
            #pragma unroll
            for (int j = 0; j < 8; ++j)
                xw[j] = (unsigned)__shfl_xor((int)wds[j], 32);
            #pragma unroll
            for (int ks = 0; ks < 2; ++ks) {
                // B-frag: lane needs keys kbbase + ks*16 + hi*8 + 0..7 of its q-row
                u32x4 uu;
                uu[0] = hi ? xw[4 * ks + 2]  : wds[4 * ks + 0];
                uu[1] = hi ? xw[4 * ks + 3]  : wds[4 * ks + 1];
                uu[2] = hi ? wds[4 * ks + 2] : xw[4 * ks + 0];
                uu[3] = hi ? wds[4 * ks + 3] : xw[4 * ks + 1];
                bf8 pf = __builtin_bit_cast(bf8, uu);
                bf8 v0 = *(const bf8*)(&Vt[l31 * LDK        + kbbase + ks * 16 + hi * 8]);
                bf8 v1 = *(const bf8*)(&Vt[(32 + l31) * LDK + kbbase + ks * 16 + hi * 8]);
                acc0 = __builtin_amdgcn_mfma_f32_32x32x16_bf16(v0, pf, acc0, 0, 0, 0);
                acc1 = __builtin_amdgcn_mfma_f32_32x32x16_bf16(v1, pf, acc1, 0, 0, 0);
            }
        };
        do_kb(p0, 0);
        do_kb(p1, 32);
        rs += __shfl_xor(rs, 32);
        lrun += rs;
    }

    // ---- epilogue: O[q][d] = acc[d][q]/l ; reg r -> d = (r&3)+8*(r>>2)+4*hi ----
    float inv = 1.0f / lrun;
    float* op = out + base + (size_t)qrow * D_DIM;
    #pragma unroll
    for (int g = 0; g < 4; ++g) {
        int d0 = g * 8 + hi * 4;
        float4 s0, s1;
        s0.x = acc0[4 * g + 0] * inv; s0.y = acc0[4 * g + 1] * inv;
        s0.z = acc0[4 * g + 2] * inv; s0.w = acc0[4 * g + 3] * inv;
        s1.x = acc1[4 * g + 0] * inv; s1.y = acc1[4 * g + 1] * inv;
        s1.z = acc1[4 * g + 2] * inv; s1.w = acc1[4 * g + 3] * inv;
        *(float4*)(op + d0)      = s0;
        *(float4*)(op + 32 + d0) = s1;
    }
}

extern "C" void kernel_launch(void* const* d_in, const int* in_sizes, int n_in,
                              void* d_out, int out_size, void* d_ws, size_t ws_size,
                              hipStream_t stream) {
    (void)in_sizes; (void)n_in; (void)d_ws; (void)ws_size; (void)out_size;
    const float* q    = (const float*)d_in[0];
    const float* k    = (const float*)d_in[1];
    const float* v    = (const float*)d_in[2];
    const int*   mask = (const int*)d_in[3];
    // d_in[4] = dropout, identity in eval reference.
    float* out = (float*)d_out;

    dim3 grid(64, 16);
    dim3 block(256);
    sdpa_kernel<<<grid, block, 0, stream>>>(q, k, v, mask, out);
}